// Round 1
// baseline (664.559 us; speedup 1.0000x reference)
//
#include <hip/hip_runtime.h>
#include <math.h>

#define N_SAMPLES 65536
#define N_FRAMES  128
#define NUM_COEFF 6
#define NUM_ACTIVE 7
#define NSEG      126        // N_FRAMES - 2 (inner tridiagonal size)
#define VEC_SIZE  808        // int(44100//55) + NUM_ACTIVE

// ---- workspace layout (byte offsets) ----
// Yall[7][128] floats : col 0 = delay_len_frames, cols 1..6 = coeff_frames
#define WS_Y     0
// Mall[7][128] floats : spline second derivatives (natural: M[0]=M[127]=0)
#define WS_M     3584
#define WS_ZMIN  7168        // int, min over t of z[t]
#define WS_X     7680        // float x[65536] (exc-filtered burst)
#define WS_VALS  269824      // float vals8[65536][8] (7 taps + pad), 16B aligned
#define WS_Z     2366976     // int z[65536]
// total: 2,629,120 bytes

// ---------------------------------------------------------------------------
// Kernel A: coeff frames (sigmoid/normalize) + Thomas solve for both splines
// ---------------------------------------------------------------------------
__global__ __launch_bounds__(128) void k_setup(
    const float* __restrict__ delay_len,
    const float* __restrict__ raw_gain,
    const float* __restrict__ raw_coeff,
    float* __restrict__ ws)
{
    __shared__ double cp[NSEG];          // shared c' of the (1,4,1) Thomas sweep
    __shared__ double dp[7][NSEG];       // per-column d'
    float* Y = ws + WS_Y / 4;            // [7][128]
    float* M = ws + WS_M / 4;            // [7][128]
    int* zmin = (int*)((char*)ws + WS_ZMIN);

    const int tid = threadIdx.x;
    if (tid < N_FRAMES) {
        float s[NUM_COEFF];
        float sum = 0.f;
        for (int j = 0; j < NUM_COEFF; ++j) {
            s[j] = 1.f / (1.f + expf(-raw_coeff[tid * NUM_COEFF + j]));
            sum += s[j];
        }
        const float gain = 1.f / (1.f + expf(-raw_gain[0]));
        for (int j = 0; j < NUM_COEFF; ++j)
            Y[(1 + j) * N_FRAMES + tid] = s[j] / sum * gain;
        Y[0 * N_FRAMES + tid] = delay_len[tid];
    }
    if (tid == 0) *zmin = 0x7fffffff;
    __syncthreads();

    if (tid == 0) {
        cp[0] = 0.25;
        for (int i = 1; i < NSEG; ++i) cp[i] = 1.0 / (4.0 - cp[i - 1]);
    }
    __syncthreads();

    if (tid < 7) {
        const float* y = Y + tid * N_FRAMES;
        const double inv_h2 = 127.0 * 127.0;   // 1/h^2, h = 1/127
        // forward sweep
        {
            double r0 = 6.0 * ((double)y[2] - 2.0 * (double)y[1] + (double)y[0]) * inv_h2;
            dp[tid][0] = r0 * 0.25;
        }
        for (int i = 1; i < NSEG; ++i) {
            double ri = 6.0 * ((double)y[i + 2] - 2.0 * (double)y[i + 1] + (double)y[i]) * inv_h2;
            dp[tid][i] = (ri - dp[tid][i - 1]) / (4.0 - cp[i - 1]);
        }
        // back substitution; M[0] = M[127] = 0 (natural)
        float* Mc = M + tid * N_FRAMES;
        Mc[0] = 0.f;
        Mc[N_FRAMES - 1] = 0.f;
        double mi = dp[tid][NSEG - 1];
        Mc[NSEG] = (float)mi;
        for (int i = NSEG - 2; i >= 0; --i) {
            mi = dp[tid][i] - cp[i] * mi;
            Mc[i + 1] = (float)mi;
        }
    }
}

// ---------------------------------------------------------------------------
// Kernel B: per-sample spline eval -> delay, z, alfa, vals[7]; atomicMin(z)
// ---------------------------------------------------------------------------
__global__ __launch_bounds__(256) void k_spline(float* __restrict__ ws)
{
    const int t = blockIdx.x * 256 + threadIdx.x;
    const float* Y = ws + WS_Y / 4;
    const float* M = ws + WS_M / 4;
    int* zmin = (int*)((char*)ws + WS_ZMIN);
    float* vals8 = ws + WS_VALS / 4;
    int* zarr = (int*)((char*)ws + WS_Z);

    const float h = 1.0f / 127.0f;
    const float tf = (float)t * (1.0f / 65535.0f);
    int idx = (int)floorf(tf * 127.0f);
    idx = min(max(idx, 0), 126);
    const float s = tf - (float)idx * h;
    const float s2 = s * s;
    const float s3 = s2 * s;

    float out[7];
#pragma unroll
    for (int c = 0; c < 7; ++c) {
        const float yi  = Y[c * N_FRAMES + idx];
        const float yi1 = Y[c * N_FRAMES + idx + 1];
        const float Mi  = M[c * N_FRAMES + idx];
        const float Mi1 = M[c * N_FRAMES + idx + 1];
        const float b = (yi1 - yi) / h - h * (2.f * Mi + Mi1) / 6.f;
        out[c] = yi + b * s + 0.5f * Mi * s2 + (Mi1 - Mi) * s3 / (6.f * h);
    }
    const float delay = out[0];
    int z = (int)floorf(delay);
    const float alfa = delay - (float)z;          // alfa uses unclamped floor (as ref)
    z = min(max(z, 0), VEC_SIZE - NUM_ACTIVE);    // dynamic_slice clamp

    float v[8];
    v[0] = -((1.f - alfa) * out[1]);
#pragma unroll
    for (int j = 1; j <= 5; ++j)
        v[j] = -(alfa * out[j] + (1.f - alfa) * out[j + 1]);
    v[6] = -(alfa * out[6]);
    v[7] = 0.f;

    float4* vp = (float4*)(vals8 + (size_t)t * 8);
    vp[0] = make_float4(v[0], v[1], v[2], v[3]);
    vp[1] = make_float4(v[4], v[5], v[6], v[7]);
    zarr[t] = z;

    __shared__ int bmin;
    if (threadIdx.x == 0) bmin = 0x7fffffff;
    __syncthreads();
    atomicMin(&bmin, z);
    __syncthreads();
    if (threadIdx.x == 0) atomicMin(zmin, bmin);
}

// ---------------------------------------------------------------------------
// Kernel C: exc first-order IIR x[t] = burst[t] - a1[t]*x[t-1] via affine scan
// ---------------------------------------------------------------------------
__global__ __launch_bounds__(1024) void k_exc(
    const float* __restrict__ exc,
    const float* __restrict__ burst,
    float* __restrict__ ws)
{
    __shared__ float sm[1024], sc[1024];
    const int k = threadIdx.x;
    float* x = ws + WS_X / 4;
    const int base = k * 64;

    // local affine aggregate: f(y) = (-a)*y + b, composed left-to-right
    float m = 1.f, c = 0.f;
    for (int i = 0; i < 64; ++i) {
        const float a = exc[base + i];
        const float b = burst[base + i];
        m = -a * m;
        c = -a * c + b;
    }
    sm[k] = m; sc[k] = c;
    __syncthreads();

    // Kogge-Stone inclusive scan over 1024 affine pairs
    for (int off = 1; off < 1024; off <<= 1) {
        const float cm = sm[k], cc = sc[k];
        float pm = 1.f, pc = 0.f;
        if (k >= off) { pm = sm[k - off]; pc = sc[k - off]; }
        __syncthreads();
        if (k >= off) { sm[k] = cm * pm; sc[k] = cm * pc + cc; }
        __syncthreads();
    }

    // exclusive prefix applied to initial state 0 gives x[base-1]
    float y = (k == 0) ? 0.f : sc[k - 1];
    for (int i = 0; i < 64; ++i) {
        const float a = exc[base + i];
        y = burst[base + i] - a * y;
        x[base + i] = y;
    }
}

// ---------------------------------------------------------------------------
// Kernel D: chunked Karplus-Strong recurrence, single workgroup.
// Chunk size C = min(z_min+1, 128): within a chunk every sample's taps
// (lags >= z+1 >= C) land strictly in previous chunks -> parallel per chunk.
// History ring in LDS (1024 >= max lag 808 + chunk 128). Zero-initialized
// ring slots serve the y[<0] = 0 taps (they are written only at t > t_read).
// ---------------------------------------------------------------------------
__global__ __launch_bounds__(128) void k_ks(
    const float* __restrict__ ws_c,
    float* __restrict__ out)
{
    __shared__ float ring[1024];
    const int lane = threadIdx.x;
    for (int i = lane; i < 1024; i += 128) ring[i] = 0.f;

    const float* x = ws_c + WS_X / 4;
    const float4* vals = (const float4*)((const char*)ws_c + WS_VALS);
    const int* zarr = (const int*)((const char*)ws_c + WS_Z);
    int zmin = *(const int*)((const char*)ws_c + WS_ZMIN);
    int C = zmin + 1;
    if (C > 128) C = 128;
    if (C < 1) C = 1;
    __syncthreads();

    const int nch = (N_SAMPLES + C - 1) / C;

    // prefetch chunk 0
    float4 v0 = {0, 0, 0, 0}, v1 = {0, 0, 0, 0};
    float xv = 0.f; int zv = 0;
    if (lane < C) {
        const int t = lane;
        v0 = vals[(size_t)t * 2];
        v1 = vals[(size_t)t * 2 + 1];
        xv = x[t];
        zv = zarr[t];
    }

    for (int c = 0; c < nch; ++c) {
        // prefetch chunk c+1 into registers (independent of ring -> overlaps)
        const int tn = (c + 1) * C + lane;
        float4 nv0 = {0, 0, 0, 0}, nv1 = {0, 0, 0, 0};
        float nx = 0.f; int nz = 0;
        if ((lane < C) && (tn < N_SAMPLES)) {
            nv0 = vals[(size_t)tn * 2];
            nv1 = vals[(size_t)tn * 2 + 1];
            nx = x[tn];
            nz = zarr[tn];
        }

        const int tc = c * C + lane;
        if ((lane < C) && (tc < N_SAMPLES)) {
            const int base = tc - 1 - zv;   // newest tap index (j = 0)
            const float dot =
                v0.x * ring[(base    ) & 1023] +
                v0.y * ring[(base - 1) & 1023] +
                v0.z * ring[(base - 2) & 1023] +
                v0.w * ring[(base - 3) & 1023] +
                v1.x * ring[(base - 4) & 1023] +
                v1.y * ring[(base - 5) & 1023] +
                v1.z * ring[(base - 6) & 1023];
            const float y = xv - dot;
            // write slot is in [t0, t0+C): disjoint from all read slots
            // (reads are in [t0-808, t0-1], span + C < 1024) -> no intra-chunk
            // barrier needed between reads and writes.
            ring[tc & 1023] = y;
            out[tc] = y;
        }
        __syncthreads();
        v0 = nv0; v1 = nv1; xv = nx; zv = nz;
    }
}

// ---------------------------------------------------------------------------
extern "C" void kernel_launch(void* const* d_in, const int* in_sizes, int n_in,
                              void* d_out, int out_size, void* d_ws, size_t ws_size,
                              hipStream_t stream)
{
    const float* delay_len = (const float*)d_in[0];
    const float* raw_gain  = (const float*)d_in[1];
    const float* raw_coeff = (const float*)d_in[2];
    const float* exc       = (const float*)d_in[3];
    const float* burst     = (const float*)d_in[4];
    float* ws  = (float*)d_ws;
    float* out = (float*)d_out;

    hipLaunchKernelGGL(k_setup, dim3(1), dim3(128), 0, stream,
                       delay_len, raw_gain, raw_coeff, ws);
    hipLaunchKernelGGL(k_spline, dim3(256), dim3(256), 0, stream, ws);
    hipLaunchKernelGGL(k_exc, dim3(1), dim3(1024), 0, stream, exc, burst, ws);
    hipLaunchKernelGGL(k_ks, dim3(1), dim3(128), 0, stream, ws, out);
}

// Round 2
// 405.218 us; speedup vs baseline: 1.6400x; 1.6400x over previous
//
#include <hip/hip_runtime.h>
#include <math.h>

#define N_SAMPLES 65536
#define N_FRAMES  128
#define NUM_COEFF 6
#define NSEG      126        // N_FRAMES - 2
#define VEC_SIZE  808
#define ZCLAMP    (VEC_SIZE - 7)   // 801

// ---- workspace layout (byte offsets) ----
#define WS_X     0           // float x[65536]
#define WS_VALS  262144      // float vals8[65536][8]
#define WS_Z     2359296     // int z[65536]
#define WS_B     2621440     // int B[1024+16]  (min z per 64-sample block)
#define NB       1024
#define NB_PAD   16

// ---------------------------------------------------------------------------
// K1: fused coeff/spline/exc front-end. Blocks 0..255: spline (each block
// redundantly recomputes the tiny Thomas solve in LDS, then evaluates 256
// samples). Block 256: exc first-order IIR via affine scan.
// ---------------------------------------------------------------------------
__global__ __launch_bounds__(256) void k_front(
    const float* __restrict__ delay_len,
    const float* __restrict__ raw_gain,
    const float* __restrict__ raw_coeff,
    const float* __restrict__ exc,
    const float* __restrict__ burst,
    float* __restrict__ ws)
{
    float* xarr  = ws + WS_X / 4;
    float* vals8 = ws + WS_VALS / 4;
    int* zarr = (int*)((char*)ws + WS_Z);
    int* Bg   = (int*)((char*)ws + WS_B);
    const int tid = threadIdx.x;
    const int b = blockIdx.x;

    if (b == 256) {
        // ---- exc IIR: x[t] = burst[t] - a[t]*x[t-1], affine scan ----
        __shared__ float sm[256], sc[256];
        const int base = tid * 256;
        float m = 1.f, c = 0.f;
        for (int i = 0; i < 256; ++i) {
            const float a = exc[base + i];
            const float x = burst[base + i];
            m = -a * m;
            c = x - a * c;
        }
        sm[tid] = m; sc[tid] = c;
        __syncthreads();
        for (int off = 1; off < 256; off <<= 1) {
            const float cm = sm[tid], cc = sc[tid];
            float pm = 1.f, pc = 0.f;
            if (tid >= off) { pm = sm[tid - off]; pc = sc[tid - off]; }
            __syncthreads();
            if (tid >= off) { sm[tid] = cm * pm; sc[tid] = cm * pc + cc; }
            __syncthreads();
        }
        float y = (tid == 0) ? 0.f : sc[tid - 1];
        for (int i = 0; i < 256; ++i) {
            const float a = exc[base + i];
            y = burst[base + i] - a * y;
            xarr[base + i] = y;
        }
        return;
    }

    // ---- spline path ----
    __shared__ float Y[7][N_FRAMES];
    __shared__ float M[7][N_FRAMES];
    __shared__ double cp[NSEG];
    __shared__ double dp[7][NSEG];
    __shared__ int gmin[4];

    if (tid < N_FRAMES) {
        float s[NUM_COEFF];
        float sum = 0.f;
        for (int j = 0; j < NUM_COEFF; ++j) {
            s[j] = 1.f / (1.f + expf(-raw_coeff[tid * NUM_COEFF + j]));
            sum += s[j];
        }
        const float gain = 1.f / (1.f + expf(-raw_gain[0]));
        for (int j = 0; j < NUM_COEFF; ++j)
            Y[1 + j][tid] = s[j] / sum * gain;
        Y[0][tid] = delay_len[tid];
    }
    if (tid < 4) gmin[tid] = 0x7fffffff;
    __syncthreads();

    if (tid == 0) {
        cp[0] = 0.25;
        for (int i = 1; i < NSEG; ++i) cp[i] = 1.0 / (4.0 - cp[i - 1]);
    }
    __syncthreads();

    if (tid < 7) {
        const float* y = Y[tid];
        const double inv_h2 = 127.0 * 127.0;
        double prev = 6.0 * ((double)y[2] - 2.0 * (double)y[1] + (double)y[0]) * inv_h2 * 0.25;
        dp[tid][0] = prev;
        for (int i = 1; i < NSEG; ++i) {
            double ri = 6.0 * ((double)y[i + 2] - 2.0 * (double)y[i + 1] + (double)y[i]) * inv_h2;
            prev = (ri - prev) * cp[i];   // cp[i] == 1/(4 - cp[i-1])
            dp[tid][i] = prev;
        }
        float* Mc = M[tid];
        Mc[0] = 0.f; Mc[N_FRAMES - 1] = 0.f;
        double mi = dp[tid][NSEG - 1];
        Mc[NSEG] = (float)mi;
        for (int i = NSEG - 2; i >= 0; --i) {
            mi = dp[tid][i] - cp[i] * mi;
            Mc[i + 1] = (float)mi;
        }
    }
    __syncthreads();

    const int t = b * 256 + tid;
    const float h = 1.0f / 127.0f;
    const float tf = (float)t * (1.0f / 65535.0f);
    int idx = (int)floorf(tf * 127.0f);
    idx = min(max(idx, 0), 126);
    const float s = tf - (float)idx * h;
    const float s2 = s * s;
    const float s3 = s2 * s;

    float o[7];
#pragma unroll
    for (int c = 0; c < 7; ++c) {
        const float yi  = Y[c][idx];
        const float yi1 = Y[c][idx + 1];
        const float Mi  = M[c][idx];
        const float Mi1 = M[c][idx + 1];
        const float bb = (yi1 - yi) / h - h * (2.f * Mi + Mi1) / 6.f;
        o[c] = yi + bb * s + 0.5f * Mi * s2 + (Mi1 - Mi) * s3 / (6.f * h);
    }
    const float delay = o[0];
    int z = (int)floorf(delay);
    const float alfa = delay - (float)z;
    z = min(max(z, 0), ZCLAMP);

    float v[8];
    v[0] = -((1.f - alfa) * o[1]);
#pragma unroll
    for (int j = 1; j <= 5; ++j)
        v[j] = -(alfa * o[j] + (1.f - alfa) * o[j + 1]);
    v[6] = -(alfa * o[6]);
    v[7] = 0.f;

    float4* vp = (float4*)(vals8 + (size_t)t * 8);
    vp[0] = make_float4(v[0], v[1], v[2], v[3]);
    vp[1] = make_float4(v[4], v[5], v[6], v[7]);
    zarr[t] = z;

    atomicMin(&gmin[tid >> 6], z);
    __syncthreads();
    if (tid < 4) Bg[b * 4 + tid] = gmin[tid];
    if (b == 0 && tid < NB_PAD) Bg[NB + tid] = 0x7fffffff;
}

// ---------------------------------------------------------------------------
// lgkm-only workgroup barrier: does NOT drain vmcnt, so global prefetch
// loads and out[] stores stay in flight across chunk boundaries.
// ---------------------------------------------------------------------------
__device__ __forceinline__ void bar_lgkm() {
    asm volatile("s_waitcnt lgkmcnt(0)\n\ts_barrier" ::: "memory");
}

// ---------------------------------------------------------------------------
// K2: chunked KS recurrence. 2 waves (128 threads).
// Greedy 64/128-quantized chunks from per-block z-mins; chunk-start table in
// LDS; depth-3 register prefetch of (vals,x,z); doubled 2048-entry LDS ring
// so the 7 taps are contiguous dwords (ds_read2_b32).
// ---------------------------------------------------------------------------
__global__ __launch_bounds__(128) void k_ks(
    const float* __restrict__ ws_c,
    float* __restrict__ out)
{
    __shared__ float ring2[2048];
    __shared__ int Bs[NB + NB_PAD];
    __shared__ int cst[2080];
    __shared__ int meta[4];   // [0]=nch, [1]/[2]=per-wave zmin

    const int tid = threadIdx.x;
    const int lane = tid;
    const float* xarr  = ws_c + WS_X / 4;
    const float* vals8 = ws_c + WS_VALS / 4;
    const int* zarr = (const int*)((const char*)ws_c + WS_Z);
    const int* Bg   = (const int*)((const char*)ws_c + WS_B);

    for (int i = tid; i < 2048; i += 128) ring2[i] = 0.f;
    for (int i = tid; i < NB + NB_PAD; i += 128) Bs[i] = Bg[i];
    __syncthreads();

    // global z-min (for fallback mode)
    int m = 0x7fffffff;
    for (int i = tid; i < NB; i += 128) m = min(m, Bs[i]);
    for (int off = 32; off; off >>= 1) m = min(m, __shfl_down(m, off));
    if ((tid & 63) == 0) meta[1 + (tid >> 6)] = m;
    __syncthreads();
    const int zminB = min(meta[1], meta[2]);

    // per-lane flag registers: lane l holds ok128 for blocks 16l..16l+15
    const int l = tid & 63;
    int f = 0;
#pragma unroll
    for (int i = 0; i < 16; ++i) {
        const int mn = min(Bs[16 * l + i], Bs[16 * l + i + 1]);
        f |= (mn >= 127 ? 1 : 0) << i;
    }

    // wave 0 builds the chunk-start table (wave-uniform readlane walk)
    if (tid < 64) {
        const int C = (zminB >= 63) ? 0 : max(zminB + 1, 1);
        int p = 0, n = 0;
        while (p < N_SAMPLES && n < 2060) {
            if (tid == 0) cst[n] = p;
            n++;
            if (C) {
                p += C;
            } else {
                const int blk = p >> 6;
                const int fw = __builtin_amdgcn_readlane(f, blk >> 4);
                p += ((fw >> (blk & 15)) & 1) ? 128 : 64;
            }
        }
        if (tid == 0) {
            for (int i = 0; i < 16; ++i) cst[n + i] = N_SAMPLES;
            meta[0] = n;
        }
    }
    __syncthreads();
    const int nch = meta[0];

    // rolling chunk starts in registers
    int S0 = cst[0], S1 = cst[1], S2 = cst[2], S3 = cst[3];
    int S4 = cst[4], S5 = cst[5], S6 = cst[6], S7 = cst[7];

    float4 a0 = {0,0,0,0}, b0 = a0, a1 = a0, b1 = a0, a2 = a0, b2 = a0;
    float x0 = 0.f, x1 = 0.f, x2 = 0.f;
    int z0 = 0, z1 = 0, z2 = 0;

    // prologue: prefetch chunks 0..2
    { int tp = S0 + lane; if (tp < S1) { const float4* vp = (const float4*)(vals8 + (size_t)tp * 8); a0 = vp[0]; b0 = vp[1]; x0 = xarr[tp]; z0 = zarr[tp]; } }
    { int tp = S1 + lane; if (tp < S2) { const float4* vp = (const float4*)(vals8 + (size_t)tp * 8); a1 = vp[0]; b1 = vp[1]; x1 = xarr[tp]; z1 = zarr[tp]; } }
    { int tp = S2 + lane; if (tp < S3) { const float4* vp = (const float4*)(vals8 + (size_t)tp * 8); a2 = vp[0]; b2 = vp[1]; x2 = xarr[tp]; z2 = zarr[tp]; } }

#define KS_BODY(AA, BB, XX, ZZ, SA, SB, SPA, SPB)                              \
    do {                                                                       \
        const int t = (SA) + lane;                                             \
        if (t < (SB)) {                                                        \
            const int base = t - 1 - (ZZ);                                     \
            const float* P = &ring2[(base & 1023) + 1018];                     \
            const float dot = (AA).x * P[6] + (AA).y * P[5] + (AA).z * P[4]    \
                            + (AA).w * P[3] + (BB).x * P[2] + (BB).y * P[1]    \
                            + (BB).z * P[0];                                   \
            const float y = (XX) - dot;                                        \
            const int w = t & 1023;                                            \
            ring2[w] = y; ring2[w + 1024] = y;                                 \
            out[t] = y;                                                        \
        }                                                                      \
        const int tp = (SPA) + lane;                                           \
        if (tp < (SPB)) {                                                      \
            const float4* vp = (const float4*)(vals8 + (size_t)tp * 8);        \
            (AA) = vp[0]; (BB) = vp[1];                                        \
            (XX) = xarr[tp]; (ZZ) = zarr[tp];                                  \
        }                                                                      \
        bar_lgkm();                                                            \
    } while (0)

    for (int cb = 0; cb < nch; cb += 3) {
        KS_BODY(a0, b0, x0, z0, S0, S1, S3, S4);
        KS_BODY(a1, b1, x1, z1, S1, S2, S4, S5);
        KS_BODY(a2, b2, x2, z2, S2, S3, S5, S6);
        S0 = S3; S1 = S4; S2 = S5; S3 = S6; S4 = S7;
        S5 = cst[cb + 8]; S6 = cst[cb + 9]; S7 = cst[cb + 10];
    }
#undef KS_BODY
}

// ---------------------------------------------------------------------------
extern "C" void kernel_launch(void* const* d_in, const int* in_sizes, int n_in,
                              void* d_out, int out_size, void* d_ws, size_t ws_size,
                              hipStream_t stream)
{
    const float* delay_len = (const float*)d_in[0];
    const float* raw_gain  = (const float*)d_in[1];
    const float* raw_coeff = (const float*)d_in[2];
    const float* exc       = (const float*)d_in[3];
    const float* burst     = (const float*)d_in[4];
    float* ws  = (float*)d_ws;
    float* out = (float*)d_out;

    hipLaunchKernelGGL(k_front, dim3(257), dim3(256), 0, stream,
                       delay_len, raw_gain, raw_coeff, exc, burst, ws);
    hipLaunchKernelGGL(k_ks, dim3(1), dim3(128), 0, stream, ws, out);
}